// Round 6
// baseline (1081.843 us; speedup 1.0000x reference)
//
#include <hip/hip_runtime.h>
#include <cstdint>
#include <cstddef>

// Shapes: B=4, NP=512, PS=16, D=1024, NH=4, HD=256, PH=4, PHD=256, K=5
// Rows of activation matrix: B*NP*PS = 32768. Patches: B*NP = 2048.

typedef __bf16 bf16x8 __attribute__((ext_vector_type(8)));
typedef float floatx4 __attribute__((ext_vector_type(4)));

#define DEV static __device__ __forceinline__

DEV unsigned short f2bf(float f) {
  union { float f; unsigned u; } x; x.f = f;
  unsigned r = x.u + 0x7fffu + ((x.u >> 16) & 1u);  // RNE
  return (unsigned short)(r >> 16);
}
DEV float bf2f(unsigned short b) {
  union { unsigned u; float f; } x; x.u = ((unsigned)b) << 16;
  return x.f;
}
DEV float silu_f(float v) { return v / (1.f + __expf(-v)); }

// async global->LDS, 16 bytes per lane. LDS dest is wave-uniform base + lane*16.
DEV void gl_lds16(const unsigned short* g, unsigned short* l) {
  __builtin_amdgcn_global_load_lds(
      (const __attribute__((address_space(1))) void*)g,
      (__attribute__((address_space(3))) void*)l, 16, 0, 0);
}

// raw barrier WITHOUT the compiler's vmcnt(0)/lgkmcnt(0) drain. "memory"
// clobber pins ordering of LDS reads / DMA issues across it at compile time.
DEV void raw_barrier() { asm volatile("s_barrier" ::: "memory"); }
// partial VMEM wait: block until <= N DMAs outstanding (AITER-style).
template <int N> DEV void waitcnt_vm() {
  if constexpr (N == 0) asm volatile("s_waitcnt vmcnt(0)" ::: "memory");
  else if constexpr (N == 6) asm volatile("s_waitcnt vmcnt(6)" ::: "memory");
  else if constexpr (N == 8) asm volatile("s_waitcnt vmcnt(8)" ::: "memory");
  else static_assert(N == 0 || N == 6 || N == 8, "add literal");
}

// block = 256 threads (4 waves); returns full-block sum to all threads
DEV float block_reduce_sum(float v) {
  #pragma unroll
  for (int o = 32; o > 0; o >>= 1) v += __shfl_down(v, o, 64);
  __shared__ float s[4];
  int w = threadIdx.x >> 6;
  if ((threadIdx.x & 63) == 0) s[w] = v;
  __syncthreads();
  return s[0] + s[1] + s[2] + s[3];
}

// ---------------- weight convert fp32 -> bf16 (all weights, one launch) -----
struct CvtArgs {
  const float* src[7];
  unsigned short* dst[7];
  int blkoff[8];  // block ranges per weight (1024 elems per block)
};
__global__ __launch_bounds__(256) void cvt_all(CvtArgs a) {
  int b = blockIdx.x;
  int w = 0;
  #pragma unroll
  for (int i = 0; i < 6; i++) w += (b >= a.blkoff[i + 1]) ? 1 : 0;
  int i = (b - a.blkoff[w]) * 1024 + threadIdx.x * 4;
  float4 v = *(const float4*)(a.src[w] + i);
  ushort4 o;
  o.x = f2bf(v.x); o.y = f2bf(v.y); o.z = f2bf(v.z); o.w = f2bf(v.w);
  *(ushort4*)(a.dst[w] + i) = o;
}

// ---------------- x = rmsnorm(pbe + local_pos) -> bf16 ----------------
__global__ __launch_bounds__(256) void prep_kernel(const float* __restrict__ pbe,
                                                   const float* __restrict__ pos,
                                                   unsigned short* __restrict__ xn) {
  int row = blockIdx.x;              // 0..32767
  int t = row & 15;                  // position within patch
  const float* ip = pbe + (size_t)row * 1024;
  const float* pp = pos + (size_t)t * 1024;
  int c = threadIdx.x * 4;
  float4 v = *(const float4*)(ip + c);
  float4 p = *(const float4*)(pp + c);
  v.x += p.x; v.y += p.y; v.z += p.z; v.w += p.w;
  float ss = v.x * v.x + v.y * v.y + v.z * v.z + v.w * v.w;
  ss = block_reduce_sum(ss);
  float sc = rsqrtf(ss * (1.f / 1024.f) + 1.1920929e-7f);
  ushort4 o;
  o.x = f2bf(v.x * sc); o.y = f2bf(v.y * sc); o.z = f2bf(v.z * sc); o.w = f2bf(v.w * sc);
  *(ushort4*)(xn + (size_t)row * 1024 + c) = o;
}

// ---------------- generic rmsnorm over D=1024 ----------------
DEV float ldval(const float* p, size_t i) { return p[i]; }
DEV float ldval(const unsigned short* p, size_t i) { return bf2f(p[i]); }
DEV void stval(float* p, size_t i, float v) { p[i] = v; }
DEV void stval(unsigned short* p, size_t i, float v) { p[i] = f2bf(v); }

template <typename TI, typename TO>
__global__ __launch_bounds__(256) void rmsnorm_kernel(const TI* __restrict__ in,
                                                      TO* __restrict__ out) {
  size_t row = blockIdx.x;
  const TI* ip = in + row * 1024;
  TO* op = out + row * 1024;
  int c = threadIdx.x * 4;
  float v[4]; float ss = 0.f;
  #pragma unroll
  for (int j = 0; j < 4; j++) { v[j] = ldval(ip, c + j); ss += v[j] * v[j]; }
  ss = block_reduce_sum(ss);
  float sc = rsqrtf(ss * (1.f / 1024.f) + 1.1920929e-7f);
  #pragma unroll
  for (int j = 0; j < 4; j++) stval(op, c + j, v[j] * sc);
}

// ===== GEMM: wave-specialized producer/consumer, BK=64, DEPTH-3 pipeline ====
// 512 threads: waves 0-3 compute 64x(TN/2) tiles, waves 4-7 stage via
// global_load_lds into TRIPLE-buffered LDS. Producers issue batch for iter
// it+2, then s_waitcnt vmcnt(NDMA) -> waits only for the it+1 batch (issued a
// full iteration earlier) -> DMA latency pipelines across iterations. Raw
// s_barrier (no compiler vmcnt(0) drain). Consumer safety: ds_read->MFMA
// lgkmcnt deps complete before barrier arrival; depth-3 separates its reads
// from the overwrite by one barrier.
// LDS rows = 64 elems (128 B), XOR swizzle on GLOBAL side: 16B chunk slot s
// holds global chunk s^(row&7); fragment reads hit banks 2-way (free, m136).

// stage R rows of a 64-elem-wide tile; 4 producer waves (pw 0-3) split rows.
template <int R>
DEV void stage_rows(const unsigned short* __restrict__ src, int ldK,
                    unsigned short* lds, int k0, int pw, int lane) {
  constexpr int PER_WAVE = R / 32;  // DMAs per wave (each DMA = 8 rows)
  #pragma unroll
  for (int d = 0; d < PER_WAVE; d++) {
    int di = pw * PER_WAVE + d;
    int r = di * 8 + (lane >> 3);
    int c = (lane & 7) ^ (r & 7);
    gl_lds16(src + (size_t)r * ldK + k0 + c * 8, lds + di * 512);
  }
}
// LDS elem offset of global chunk g (0..7) at row
DEV int frag_off64(int row, int g) {
  return row * 64 + ((g ^ (row & 7)) * 8);
}

// C[M,N] = A[M,K] @ W[N,K]^T (bf16 in, fp32 acc). Grid: (N/TN, M/TM).
// EPI: 0=store fp32, 1=store bf16, 2=silu->bf16, 3=+res(bf16)->bf16, 4=+res(fp32)->bf16
template <int EPI, int TM, int TN>
__global__ __launch_bounds__(512) void gemm_ws3(
    const unsigned short* __restrict__ A, const unsigned short* __restrict__ Bw,
    int M, int N, int K,
    float* __restrict__ outF, unsigned short* __restrict__ outB,
    const unsigned short* __restrict__ resB, const float* __restrict__ resF) {
  constexpr int AI = TM / 32;
  constexpr int BJ = TN / 32;
  constexpr int NDMA = (TM + TN) / 8 / 4;  // DMAs per producer wave per iter
  __shared__ __align__(16) unsigned short As[3][TM * 64];
  __shared__ __align__(16) unsigned short Bs[3][TN * 64];
  const int tid = threadIdx.x;
  const int bm = blockIdx.y * TM, bn = blockIdx.x * TN;
  const int wave = tid >> 6, lane = tid & 63;
  const bool producer = wave >= 4;
  const int pw = wave & 3;
  const int wy = (wave & 3) >> 1, wx = wave & 1;
  const int l15 = lane & 15, quad = lane >> 4;

  const unsigned short* Ab = A + (size_t)bm * K;
  const unsigned short* Bb = Bw + (size_t)bn * K;

  floatx4 acc[AI][BJ];
  #pragma unroll
  for (int i = 0; i < AI; i++)
    #pragma unroll
    for (int j = 0; j < BJ; j++)
      #pragma unroll
      for (int r = 0; r < 4; r++) acc[i][j][r] = 0.f;

  int arow[AI], brow[BJ];
  #pragma unroll
  for (int i = 0; i < AI; i++) arow[i] = wy * (TM / 2) + i * 16 + l15;
  #pragma unroll
  for (int j = 0; j < BJ; j++) brow[j] = wx * (TN / 2) + j * 16 + l15;

  const int iters = K >> 6;
  if (producer) {
    stage_rows<TM>(Ab, K, As[0], 0, pw, lane);
    stage_rows<TN>(Bb, K, Bs[0], 0, pw, lane);
    stage_rows<TM>(Ab, K, As[1], 64, pw, lane);
    stage_rows<TN>(Bb, K, Bs[1], 64, pw, lane);
    waitcnt_vm<NDMA>();  // buf0 landed; buf1 still in flight
  }
  raw_barrier();
  int cur = 0, nx2 = 2;
  for (int it = 0; it < iters; ++it) {
    if (producer) {
      if (it + 2 < iters) {
        stage_rows<TM>(Ab, K, As[nx2], (it + 2) << 6, pw, lane);
        stage_rows<TN>(Bb, K, Bs[nx2], (it + 2) << 6, pw, lane);
        waitcnt_vm<NDMA>();  // wait for buf it+1 (issued last iter)
      } else {
        waitcnt_vm<0>();
      }
    } else {
      #pragma unroll
      for (int h = 0; h < 2; h++) {
        bf16x8 afr[AI], bfr[BJ];
        #pragma unroll
        for (int i = 0; i < AI; i++)
          afr[i] = *(const bf16x8*)&As[cur][frag_off64(arow[i], h * 4 + quad)];
        #pragma unroll
        for (int j = 0; j < BJ; j++)
          bfr[j] = *(const bf16x8*)&Bs[cur][frag_off64(brow[j], h * 4 + quad)];
        #pragma unroll
        for (int i = 0; i < AI; i++)
          #pragma unroll
          for (int j = 0; j < BJ; j++)
            acc[i][j] = __builtin_amdgcn_mfma_f32_16x16x32_bf16(afr[i], bfr[j], acc[i][j], 0, 0, 0);
      }
    }
    raw_barrier();
    cur = (cur == 2) ? 0 : cur + 1;
    nx2 = (nx2 == 2) ? 0 : nx2 + 1;
  }

  if (producer) return;
  #pragma unroll
  for (int i = 0; i < AI; i++)
    #pragma unroll
    for (int j = 0; j < BJ; j++) {
      int gm = bm + wy * (TM / 2) + i * 16 + quad * 4;
      int gn = bn + wx * (TN / 2) + j * 16 + l15;
      #pragma unroll
      for (int r = 0; r < 4; r++) {
        float v = acc[i][j][r];
        size_t idx = (size_t)(gm + r) * N + gn;
        if (EPI == 0) outF[idx] = v;
        else if (EPI == 1) outB[idx] = f2bf(v);
        else if (EPI == 2) outB[idx] = f2bf(silu_f(v));
        else if (EPI == 3) outB[idx] = f2bf(v + bf2f(resB[idx]));
        else if (EPI == 4) outB[idx] = f2bf(v + resF[idx]);
      }
    }
}

// -- wave-specialized dual GEMM, depth-3: h = silu(A@Wg^T) * (A@Wi^T) --------
// Block tile 128(M) x 64(N); consumer wave 64x32 per output (64 acc regs).
__global__ __launch_bounds__(512) void gemm_dual_ws3(
    const unsigned short* __restrict__ A, const unsigned short* __restrict__ Bg,
    const unsigned short* __restrict__ Bi, int M, int N, int K,
    unsigned short* __restrict__ outH) {
  __shared__ __align__(16) unsigned short As[3][128 * 64];
  __shared__ __align__(16) unsigned short Gs[3][64 * 64];
  __shared__ __align__(16) unsigned short Is[3][64 * 64];
  const int tid = threadIdx.x;
  const int bm = blockIdx.y * 128, bn = blockIdx.x * 64;
  const int wave = tid >> 6, lane = tid & 63;
  const bool producer = wave >= 4;
  const int pw = wave & 3;
  const int wy = (wave & 3) >> 1, wx = wave & 1;
  const int l15 = lane & 15, quad = lane >> 4;

  const unsigned short* Ab = A + (size_t)bm * K;
  const unsigned short* Gb = Bg + (size_t)bn * K;
  const unsigned short* Ib = Bi + (size_t)bn * K;

  floatx4 accg[4][2], acci[4][2];
  #pragma unroll
  for (int i = 0; i < 4; i++)
    #pragma unroll
    for (int j = 0; j < 2; j++)
      #pragma unroll
      for (int r = 0; r < 4; r++) { accg[i][j][r] = 0.f; acci[i][j][r] = 0.f; }

  int arow[4], brow[2];
  #pragma unroll
  for (int i = 0; i < 4; i++) arow[i] = wy * 64 + i * 16 + l15;
  #pragma unroll
  for (int j = 0; j < 2; j++) brow[j] = wx * 32 + j * 16 + l15;

  const int iters = K >> 6;
  if (producer) {
    stage_rows<128>(Ab, K, As[0], 0, pw, lane);
    stage_rows<64>(Gb, K, Gs[0], 0, pw, lane);
    stage_rows<64>(Ib, K, Is[0], 0, pw, lane);
    stage_rows<128>(Ab, K, As[1], 64, pw, lane);
    stage_rows<64>(Gb, K, Gs[1], 64, pw, lane);
    stage_rows<64>(Ib, K, Is[1], 64, pw, lane);
    waitcnt_vm<8>();
  }
  raw_barrier();
  int cur = 0, nx2 = 2;
  for (int it = 0; it < iters; ++it) {
    if (producer) {
      if (it + 2 < iters) {
        stage_rows<128>(Ab, K, As[nx2], (it + 2) << 6, pw, lane);
        stage_rows<64>(Gb, K, Gs[nx2], (it + 2) << 6, pw, lane);
        stage_rows<64>(Ib, K, Is[nx2], (it + 2) << 6, pw, lane);
        waitcnt_vm<8>();
      } else {
        waitcnt_vm<0>();
      }
    } else {
      #pragma unroll
      for (int h = 0; h < 2; h++) {
        bf16x8 afr[4], gfr[2], ifr[2];
        #pragma unroll
        for (int i = 0; i < 4; i++)
          afr[i] = *(const bf16x8*)&As[cur][frag_off64(arow[i], h * 4 + quad)];
        #pragma unroll
        for (int j = 0; j < 2; j++) {
          gfr[j] = *(const bf16x8*)&Gs[cur][frag_off64(brow[j], h * 4 + quad)];
          ifr[j] = *(const bf16x8*)&Is[cur][frag_off64(brow[j], h * 4 + quad)];
        }
        #pragma unroll
        for (int i = 0; i < 4; i++)
          #pragma unroll
          for (int j = 0; j < 2; j++) {
            accg[i][j] = __builtin_amdgcn_mfma_f32_16x16x32_bf16(afr[i], gfr[j], accg[i][j], 0, 0, 0);
            acci[i][j] = __builtin_amdgcn_mfma_f32_16x16x32_bf16(afr[i], ifr[j], acci[i][j], 0, 0, 0);
          }
      }
    }
    raw_barrier();
    cur = (cur == 2) ? 0 : cur + 1;
    nx2 = (nx2 == 2) ? 0 : nx2 + 1;
  }

  if (producer) return;
  #pragma unroll
  for (int i = 0; i < 4; i++)
    #pragma unroll
    for (int j = 0; j < 2; j++) {
      int gm = bm + wy * 64 + i * 16 + quad * 4;
      int gn = bn + wx * 32 + j * 16 + l15;
      #pragma unroll
      for (int r = 0; r < 4; r++) {
        size_t idx = (size_t)(gm + r) * N + gn;
        outH[idx] = f2bf(silu_f(accg[i][j][r]) * acci[i][j][r]);
      }
    }
}

// ------- fused depthwise causal conv (K=5) + residual + rmsnorm -------
// outputs x2 = h + conv(h) and x2n = rmsnorm(x2). Vectorized LDS taps.
#define HS_LD 1040  // skewed row stride (elems): 2080 B -> rows shift 8 banks
__global__ __launch_bounds__(256) void conv_rms_kernel(const unsigned short* __restrict__ h,
                                                       const float* __restrict__ cw,
                                                       unsigned short* __restrict__ x2,
                                                       unsigned short* __restrict__ x2n) {
  int patch = blockIdx.x;  // 0..2047
  __shared__ __align__(16) unsigned short hs[16 * HS_LD];
  __shared__ __align__(16) float cwp[5 * 1024];  // [k][c] planes
  const int tid = threadIdx.x;
  size_t base = (size_t)patch * 16384;
  for (int idx = tid * 8; idx < 16384; idx += 256 * 8) {
    int row = idx >> 10, col = idx & 1023;
    *(uint4*)&hs[row * HS_LD + col] = *(const uint4*)&h[base + idx];
  }
  for (int i = tid; i < 5120; i += 256) {
    int c = i / 5, k = i - c * 5;
    cwp[k * 1024 + c] = cw[i];
  }
  __syncthreads();
  int t = tid >> 4;
  int lc = (tid & 15) * 8;
  float vals[8][8];
  float ss = 0.f;
  #pragma unroll
  for (int jb = 0; jb < 8; jb++) {
    int c = jb * 128 + lc;
    float tap[5][8];
    #pragma unroll
    for (int k = 0; k < 5; k++) {
      int tt = t + k - 4;
      if (tt >= 0) {
        uint4 v = *(const uint4*)&hs[tt * HS_LD + c];
        const unsigned short* vp = (const unsigned short*)&v;
        #pragma unroll
        for (int i = 0; i < 8; i++) tap[k][i] = bf2f(vp[i]);
      } else {
        #pragma unroll
        for (int i = 0; i < 8; i++) tap[k][i] = 0.f;
      }
    }
    float w[5][8];
    #pragma unroll
    for (int k = 0; k < 5; k++) {
      float4 a = *(const float4*)&cwp[k * 1024 + c];
      float4 b = *(const float4*)&cwp[k * 1024 + c + 4];
      w[k][0] = a.x; w[k][1] = a.y; w[k][2] = a.z; w[k][3] = a.w;
      w[k][4] = b.x; w[k][5] = b.y; w[k][6] = b.z; w[k][7] = b.w;
    }
    #pragma unroll
    for (int i = 0; i < 8; i++) {
      float acc = tap[4][i];  // residual (tap k=4 is row t itself)
      #pragma unroll
      for (int k = 0; k < 5; k++) acc += w[k][i] * tap[k][i];
      vals[jb][i] = acc;
      ss += acc * acc;
    }
  }
  ss += __shfl_down(ss, 8, 16);
  ss += __shfl_down(ss, 4, 16);
  ss += __shfl_down(ss, 2, 16);
  ss += __shfl_down(ss, 1, 16);
  ss = __shfl(ss, 0, 16);
  float sc = rsqrtf(ss * (1.f / 1024.f) + 1.1920929e-7f);
  #pragma unroll
  for (int jb = 0; jb < 8; jb++) {
    ushort4 o2[2], on[2];
    #pragma unroll
    for (int i = 0; i < 8; i++) {
      ((unsigned short*)o2)[i] = f2bf(vals[jb][i]);
      ((unsigned short*)on)[i] = f2bf(vals[jb][i] * sc);
    }
    size_t off = base + (size_t)t * 1024 + jb * 128 + lc;
    *(uint4*)&x2[off] = *(uint4*)o2;
    *(uint4*)&x2n[off] = *(uint4*)on;
  }
}

// ---------------- per-patch per-head attention (PS=16, HD=256) ----------------
__global__ __launch_bounds__(256) void attn_kernel(const unsigned short* __restrict__ qkv,
                                                   unsigned short* __restrict__ sa) {
  int patch = blockIdx.x;  // 0..2047
  int head = blockIdx.y;   // 0..3
  const int tid = threadIdx.x;
  __shared__ float qs[16][260], ks[16][260], vs[16][260];
  __shared__ float sc[16][16];
  size_t base = (size_t)patch * 16 * 3072 + (size_t)head * 256;
  for (int idx = tid * 8; idx < 16 * 256; idx += 256 * 8) {
    int t = idx >> 8, d = idx & 255;
    size_t roff = base + (size_t)t * 3072 + d;
    uint4 qv = *(const uint4*)&qkv[roff];
    uint4 kv = *(const uint4*)&qkv[roff + 1024];
    uint4 vv = *(const uint4*)&qkv[roff + 2048];
    const unsigned short* qp = (const unsigned short*)&qv;
    const unsigned short* kp = (const unsigned short*)&kv;
    const unsigned short* vp = (const unsigned short*)&vv;
    #pragma unroll
    for (int i = 0; i < 8; i++) {
      qs[t][d + i] = bf2f(qp[i]);
      ks[t][d + i] = bf2f(kp[i]);
      vs[t][d + i] = bf2f(vp[i]);
    }
  }
  __syncthreads();
  {
    int t = tid >> 4, kk = tid & 15;
    float s = 0.f;
    for (int d = 0; d < 256; d += 4) {
      float4 q = *(const float4*)&qs[t][d];
      float4 k = *(const float4*)&ks[kk][d];
      s += q.x * k.x + q.y * k.y + q.z * k.z + q.w * k.w;
    }
    sc[t][kk] = s * 0.0625f;  // HD^-0.5
  }
  __syncthreads();
  if (tid < 16) {
    float m = -1e30f;
    for (int kk = 0; kk < 16; kk++) m = fmaxf(m, sc[tid][kk]);
    float p[16], sum = 0.f;
    for (int kk = 0; kk < 16; kk++) { p[kk] = __expf(sc[tid][kk] - m); sum += p[kk]; }
    float inv = 1.f / sum;
    for (int kk = 0; kk < 16; kk++) sc[tid][kk] = p[kk] * inv;
  }
  __syncthreads();
  for (int idx = tid * 8; idx < 4096; idx += 256 * 8) {
    int t = idx >> 8, d = idx & 255;
    float o[8] = {0, 0, 0, 0, 0, 0, 0, 0};
    #pragma unroll
    for (int kk = 0; kk < 16; kk++) {
      float w = sc[t][kk];
      float4 v0 = *(const float4*)&vs[kk][d];
      float4 v1 = *(const float4*)&vs[kk][d + 4];
      o[0] += w * v0.x; o[1] += w * v0.y; o[2] += w * v0.z; o[3] += w * v0.w;
      o[4] += w * v1.x; o[5] += w * v1.y; o[6] += w * v1.z; o[7] += w * v1.w;
    }
    ushort4 ov[2];
    #pragma unroll
    for (int i = 0; i < 8; i++) ((unsigned short*)ov)[i] = f2bf(o[i]);
    *(uint4*)&sa[(size_t)(patch * 16 + t) * 1024 + head * 256 + d] = *(uint4*)ov;
  }
}

// -- head pooling with FUSED rmsnorm(x3) input + fused rmsnorm(pooled) out --
__global__ __launch_bounds__(256) void pool_kernel(const unsigned short* __restrict__ x3,
                                                   const float* __restrict__ wpool,
                                                   const float* __restrict__ tptr,
                                                   float* __restrict__ pooled,
                                                   unsigned short* __restrict__ pooledn) {
  int patch = blockIdx.x;  // 0..2047
  __shared__ __align__(16) unsigned short xs[16 * 1024];
  __shared__ float lg[4][16], aw[4][16], srow[16];
  const int tid = threadIdx.x;
  size_t base = (size_t)patch * 16384;
  for (int idx = tid * 8; idx < 16384; idx += 256 * 8)
    *(uint4*)&xs[idx] = *(const uint4*)&x3[base + idx];
  __syncthreads();
  {  // per-row sum of squares: row t = tid>>4, 64 elems per lane
    int t = tid >> 4, sub = tid & 15;
    float ss = 0.f;
    for (int d = sub * 64; d < sub * 64 + 64; d += 4) {
      uint2 v = *(const uint2*)&xs[t * 1024 + d];
      const unsigned short* vp = (const unsigned short*)&v;
      #pragma unroll
      for (int i = 0; i < 4; i++) { float x = bf2f(vp[i]); ss += x * x; }
    }
    ss += __shfl_down(ss, 8, 16);
    ss += __shfl_down(ss, 4, 16);
    ss += __shfl_down(ss, 2, 16);
    ss += __shfl_down(ss, 1, 16);
    if (sub == 0) srow[t] = rsqrtf(ss * (1.f / 1024.f) + 1.1920929e-7f);
  }
  __syncthreads();
  {
    int pair = tid >> 2, sub = tid & 3;
    int t = pair >> 2, hh = pair & 3;
    float s = 0.f;
    for (int d = sub * 256; d < sub * 256 + 256; d++)
      s += bf2f(xs[t * 1024 + d]) * wpool[hh * 1024 + d];
    s += __shfl_down(s, 2, 64);
    s += __shfl_down(s, 1, 64);
    if (sub == 0) {
      float temp = fmaxf(tptr[0], 0.01f);
      lg[hh][t] = s * srow[t] / temp;
    }
  }
  __syncthreads();
  if (tid < 4) {
    int hh = tid;
    float m = -1e30f;
    for (int t = 0; t < 16; t++) m = fmaxf(m, lg[hh][t]);
    float p[16], sum = 0.f;
    for (int t = 0; t < 16; t++) { p[t] = __expf(lg[hh][t] - m); sum += p[t]; }
    float inv = 1.f / sum;
    for (int t = 0; t < 16; t++) aw[hh][t] = p[t] * inv;
  }
  __syncthreads();
  float ov[4]; int cs[4];
  float ss = 0.f;
  #pragma unroll
  for (int q = 0; q < 4; q++) {
    int c = tid + q * 256;
    int hh = c >> 8;
    float o = 0.f;
    #pragma unroll
    for (int t = 0; t < 16; t++) o += aw[hh][t] * srow[t] * bf2f(xs[t * 1024 + c]);
    ov[q] = o; cs[q] = c;
    ss += o * o;
  }
  ss = block_reduce_sum(ss);
  float scn = rsqrtf(ss * (1.f / 1024.f) + 1.1920929e-7f);
  #pragma unroll
  for (int q = 0; q < 4; q++) {
    pooled[(size_t)patch * 1024 + cs[q]] = ov[q];
    pooledn[(size_t)patch * 1024 + cs[q]] = f2bf(ov[q] * scn);
  }
}

extern "C" void kernel_launch(void* const* d_in, const int* in_sizes, int n_in,
                              void* d_out, int out_size, void* d_ws, size_t ws_size,
                              hipStream_t stream) {
  (void)in_sizes; (void)n_in; (void)out_size; (void)ws_size;
  const float* pbe  = (const float*)d_in[0];   // (4,512,16,1024)
  const float* lpos = (const float*)d_in[1];   // (16,1024)
  const float* wg   = (const float*)d_in[2];
  const float* wi   = (const float*)d_in[3];
  const float* cw   = (const float*)d_in[4];   // (1024,1,5)
  const float* wqkv = (const float*)d_in[5];   // (3072,1024)
  const float* wio  = (const float*)d_in[6];
  const float* wpl  = (const float*)d_in[7];   // (4,1024)
  const float* temp = (const float*)d_in[8];
  const float* wup  = (const float*)d_in[9];
  const float* wdn  = (const float*)d_in[10];
  const float* wout = (const float*)d_in[11];
  float* outp = (float*)d_out;                 // (4,512,1024) fp32

  const int ROWS = 32768, Dm = 1024, NPAT = 2048;

  char* p = (char*)d_ws;
  auto take = [&](size_t nbytes) { void* r = (void*)p; p += (nbytes + 255) & ~(size_t)255; return r; };
  unsigned short* wg_b   = (unsigned short*)take((size_t)Dm * Dm * 2);
  unsigned short* wi_b   = (unsigned short*)take((size_t)Dm * Dm * 2);
  unsigned short* wqkv_b = (unsigned short*)take((size_t)3 * Dm * Dm * 2);
  unsigned short* wio_b  = (unsigned short*)take((size_t)Dm * Dm * 2);
  unsigned short* wup_b  = (unsigned short*)take((size_t)Dm * Dm * 2);
  unsigned short* wdn_b  = (unsigned short*)take((size_t)Dm * Dm * 2);
  unsigned short* wout_b = (unsigned short*)take((size_t)Dm * Dm * 2);
  unsigned short* slotA  = (unsigned short*)take((size_t)ROWS * Dm * 2);  // xn / x2n
  unsigned short* slotB  = (unsigned short*)take((size_t)ROWS * Dm * 2);  // h / sa
  unsigned short* slotC  = (unsigned short*)take((size_t)ROWS * Dm * 2);  // x2 / x3
  unsigned short* qkvB   = (unsigned short*)take((size_t)ROWS * 3 * Dm * 2);
  float*          pooled = (float*)take((size_t)NPAT * Dm * 4);
  unsigned short* pooledn= (unsigned short*)take((size_t)NPAT * Dm * 2);
  unsigned short* ubuf   = (unsigned short*)take((size_t)NPAT * Dm * 2);
  unsigned short* y1b    = (unsigned short*)take((size_t)NPAT * Dm * 2);
  float*          y2     = (float*)take((size_t)NPAT * Dm * 4);

  // 0. all weight conversions in one launch
  CvtArgs ca;
  ca.src[0] = wg;   ca.dst[0] = wg_b;
  ca.src[1] = wi;   ca.dst[1] = wi_b;
  ca.src[2] = wqkv; ca.dst[2] = wqkv_b;
  ca.src[3] = wio;  ca.dst[3] = wio_b;
  ca.src[4] = wup;  ca.dst[4] = wup_b;
  ca.src[5] = wdn;  ca.dst[5] = wdn_b;
  ca.src[6] = wout; ca.dst[6] = wout_b;
  int off = 0;
  for (int i = 0; i < 7; i++) { ca.blkoff[i] = off; off += (i == 2) ? 3072 : 1024; }
  ca.blkoff[7] = off;
  cvt_all<<<dim3(off), dim3(256), 0, stream>>>(ca);

  // 1. xn = rmsnorm(pbe + pos)
  prep_kernel<<<dim3(ROWS), dim3(256), 0, stream>>>(pbe, lpos, slotA);
  // 2. h = silu(xn@wg^T) * (xn@wi^T)
  gemm_dual_ws3<<<dim3(Dm / 64, ROWS / 128), dim3(512), 0, stream>>>(
      slotA, wg_b, wi_b, ROWS, Dm, Dm, slotB);
  // 3+4. x2 = h + conv(h); x2n = rmsnorm(x2)
  conv_rms_kernel<<<dim3(NPAT), dim3(256), 0, stream>>>(slotB, cw, slotC, slotA);
  // 5. qkv = x2n @ wqkv^T
  gemm_ws3<1, 128, 128><<<dim3(3 * Dm / 128, ROWS / 128), dim3(512), 0, stream>>>(
      slotA, wqkv_b, ROWS, 3 * Dm, Dm, nullptr, qkvB, nullptr, nullptr);
  // 6. sa = attention(qkv)
  attn_kernel<<<dim3(NPAT, 4), dim3(256), 0, stream>>>(qkvB, slotB);
  // 7. x3 = x2 + sa @ wio^T   (in-place into slotC)
  gemm_ws3<3, 128, 128><<<dim3(Dm / 128, ROWS / 128), dim3(512), 0, stream>>>(
      slotB, wio_b, ROWS, Dm, Dm, nullptr, slotC, slotC, nullptr);
  // 8+9+10. pooled = softmax-pool(rmsnorm(x3)); pooledn = rmsnorm(pooled)
  pool_kernel<<<dim3(NPAT), dim3(256), 0, stream>>>(slotC, wpl, temp, pooled, pooledn);
  // 11. u = silu(pooledn @ wup^T)
  gemm_ws3<2, 64, 128><<<dim3(Dm / 128, NPAT / 64), dim3(512), 0, stream>>>(
      pooledn, wup_b, NPAT, Dm, Dm, nullptr, ubuf, nullptr, nullptr);
  // 12. y1 = pooled + u @ wdn^T
  gemm_ws3<4, 64, 128><<<dim3(Dm / 128, NPAT / 64), dim3(512), 0, stream>>>(
      ubuf, wdn_b, NPAT, Dm, Dm, nullptr, y1b, nullptr, pooled);
  // 13. y2 = y1 @ wout^T
  gemm_ws3<0, 64, 128><<<dim3(Dm / 128, NPAT / 64), dim3(512), 0, stream>>>(
      y1b, wout_b, NPAT, Dm, Dm, y2, nullptr, nullptr, nullptr);
  // 14. out = rmsnorm(y2)
  rmsnorm_kernel<float, float><<<dim3(NPAT), dim3(256), 0, stream>>>(y2, outp);
}

// Round 7
// 1030.198 us; speedup vs baseline: 1.0501x; 1.0501x over previous
//
#include <hip/hip_runtime.h>
#include <cstdint>
#include <cstddef>

// Shapes: B=4, NP=512, PS=16, D=1024, NH=4, HD=256, PH=4, PHD=256, K=5
// Rows of activation matrix: B*NP*PS = 32768. Patches: B*NP = 2048.

typedef __bf16 bf16x8 __attribute__((ext_vector_type(8)));
typedef float floatx4 __attribute__((ext_vector_type(4)));

#define DEV static __device__ __forceinline__

DEV unsigned short f2bf(float f) {
  union { float f; unsigned u; } x; x.f = f;
  unsigned r = x.u + 0x7fffu + ((x.u >> 16) & 1u);  // RNE
  return (unsigned short)(r >> 16);
}
DEV float bf2f(unsigned short b) {
  union { unsigned u; float f; } x; x.u = ((unsigned)b) << 16;
  return x.f;
}
DEV float silu_f(float v) { return v / (1.f + __expf(-v)); }

// async global->LDS, 16 bytes per lane. LDS dest is wave-uniform base + lane*16.
DEV void gl_lds16(const unsigned short* g, unsigned short* l) {
  __builtin_amdgcn_global_load_lds(
      (const __attribute__((address_space(1))) void*)g,
      (__attribute__((address_space(3))) void*)l, 16, 0, 0);
}

// raw barrier WITHOUT the compiler's vmcnt(0)/lgkmcnt(0) drain.
DEV void raw_barrier() { asm volatile("s_barrier" ::: "memory"); }
// partial VMEM wait: block until <= N DMAs outstanding (per-wave counter).
template <int N> DEV void waitcnt_vm() {
  if constexpr (N == 0) asm volatile("s_waitcnt vmcnt(0)" ::: "memory");
  else if constexpr (N == 2) asm volatile("s_waitcnt vmcnt(2)" ::: "memory");
  else if constexpr (N == 4) asm volatile("s_waitcnt vmcnt(4)" ::: "memory");
  else static_assert(N == 0 || N == 2 || N == 4, "add literal");
}

// block = 256 threads (4 waves); returns full-block sum to all threads
DEV float block_reduce_sum(float v) {
  #pragma unroll
  for (int o = 32; o > 0; o >>= 1) v += __shfl_down(v, o, 64);
  __shared__ float s[4];
  int w = threadIdx.x >> 6;
  if ((threadIdx.x & 63) == 0) s[w] = v;
  __syncthreads();
  return s[0] + s[1] + s[2] + s[3];
}

// ---------------- weight convert fp32 -> bf16 (all weights, one launch) -----
struct CvtArgs {
  const float* src[7];
  unsigned short* dst[7];
  int blkoff[8];  // block ranges per weight (1024 elems per block)
};
__global__ __launch_bounds__(256) void cvt_all(CvtArgs a) {
  int b = blockIdx.x;
  int w = 0;
  #pragma unroll
  for (int i = 0; i < 6; i++) w += (b >= a.blkoff[i + 1]) ? 1 : 0;
  int i = (b - a.blkoff[w]) * 1024 + threadIdx.x * 4;
  float4 v = *(const float4*)(a.src[w] + i);
  ushort4 o;
  o.x = f2bf(v.x); o.y = f2bf(v.y); o.z = f2bf(v.z); o.w = f2bf(v.w);
  *(ushort4*)(a.dst[w] + i) = o;
}

// ---------------- x = rmsnorm(pbe + local_pos) -> bf16 ----------------
__global__ __launch_bounds__(256) void prep_kernel(const float* __restrict__ pbe,
                                                   const float* __restrict__ pos,
                                                   unsigned short* __restrict__ xn) {
  int row = blockIdx.x;              // 0..32767
  int t = row & 15;                  // position within patch
  const float* ip = pbe + (size_t)row * 1024;
  const float* pp = pos + (size_t)t * 1024;
  int c = threadIdx.x * 4;
  float4 v = *(const float4*)(ip + c);
  float4 p = *(const float4*)(pp + c);
  v.x += p.x; v.y += p.y; v.z += p.z; v.w += p.w;
  float ss = v.x * v.x + v.y * v.y + v.z * v.z + v.w * v.w;
  ss = block_reduce_sum(ss);
  float sc = rsqrtf(ss * (1.f / 1024.f) + 1.1920929e-7f);
  ushort4 o;
  o.x = f2bf(v.x * sc); o.y = f2bf(v.y * sc); o.z = f2bf(v.z * sc); o.w = f2bf(v.w * sc);
  *(ushort4*)(xn + (size_t)row * 1024 + c) = o;
}

// ---------------- generic rmsnorm over D=1024 ----------------
DEV float ldval(const float* p, size_t i) { return p[i]; }
DEV float ldval(const unsigned short* p, size_t i) { return bf2f(p[i]); }
DEV void stval(float* p, size_t i, float v) { p[i] = v; }
DEV void stval(unsigned short* p, size_t i, float v) { p[i] = f2bf(v); }

template <typename TI, typename TO>
__global__ __launch_bounds__(256) void rmsnorm_kernel(const TI* __restrict__ in,
                                                      TO* __restrict__ out) {
  size_t row = blockIdx.x;
  const TI* ip = in + row * 1024;
  TO* op = out + row * 1024;
  int c = threadIdx.x * 4;
  float v[4]; float ss = 0.f;
  #pragma unroll
  for (int j = 0; j < 4; j++) { v[j] = ldval(ip, c + j); ss += v[j] * v[j]; }
  ss = block_reduce_sum(ss);
  float sc = rsqrtf(ss * (1.f / 1024.f) + 1.1920929e-7f);
  #pragma unroll
  for (int j = 0; j < 4; j++) stval(op, c + j, v[j] * sc);
}

// ==== GEMM: wave-specialized, BK=64, MIXED-DEPTH pipeline (A x3, B x2) ====
// 512 threads: waves 0-3 compute, waves 4-7 stage via global_load_lds.
// Per iter the producer issues B(it+1) (flight = one MFMA phase; weights are
// L2-hot) and A(it+2) (flight = a full iter+; activations come from L3), then
// waits vmcnt(TM/32): drains A(it+1)+B(it+1), leaves only the newest A batch
// in flight. Raw s_barrier -> no compiler vmcnt(0) drain anywhere in the loop.
// LDS = 3*A + 2*B = 80 KB at TM=TN=128 -> 2 blocks/CU (R6's 96 KB gave 1).
// LDS rows = 64 elems; XOR swizzle on GLOBAL side: 16B chunk slot s holds
// global chunk s^(row&7); fragment reads hit banks 2-way (free, m136).

// stage R rows of a 64-elem-wide tile; 4 producer waves (pw 0-3) split rows.
template <int R>
DEV void stage_rows(const unsigned short* __restrict__ src, int ldK,
                    unsigned short* lds, int k0, int pw, int lane) {
  constexpr int PER_WAVE = R / 32;  // DMAs per wave (each DMA = 8 rows)
  #pragma unroll
  for (int d = 0; d < PER_WAVE; d++) {
    int di = pw * PER_WAVE + d;
    int r = di * 8 + (lane >> 3);
    int c = (lane & 7) ^ (r & 7);
    gl_lds16(src + (size_t)r * ldK + k0 + c * 8, lds + di * 512);
  }
}
// LDS elem offset of global chunk g (0..7) at row
DEV int frag_off64(int row, int g) {
  return row * 64 + ((g ^ (row & 7)) * 8);
}

// C[M,N] = A[M,K] @ W[N,K]^T (bf16 in, fp32 acc). Grid: (N/TN, M/TM).
// EPI: 0=store fp32, 1=store bf16, 2=silu->bf16, 3=+res(bf16)->bf16, 4=+res(fp32)->bf16
template <int EPI, int TM, int TN>
__global__ __launch_bounds__(512, 4) void gemm_ws(
    const unsigned short* __restrict__ A, const unsigned short* __restrict__ Bw,
    int M, int N, int K,
    float* __restrict__ outF, unsigned short* __restrict__ outB,
    const unsigned short* __restrict__ resB, const float* __restrict__ resF) {
  constexpr int AI = TM / 32;
  constexpr int BJ = TN / 32;
  __shared__ __align__(16) unsigned short As[3][TM * 64];
  __shared__ __align__(16) unsigned short Bs[2][TN * 64];
  const int tid = threadIdx.x;
  const int bm = blockIdx.y * TM, bn = blockIdx.x * TN;
  const int wave = tid >> 6, lane = tid & 63;
  const bool producer = wave >= 4;
  const int pw = wave & 3;
  const int wy = (wave & 3) >> 1, wx = wave & 1;
  const int l15 = lane & 15, quad = lane >> 4;

  const unsigned short* Ab = A + (size_t)bm * K;
  const unsigned short* Bb = Bw + (size_t)bn * K;

  floatx4 acc[AI][BJ];
  #pragma unroll
  for (int i = 0; i < AI; i++)
    #pragma unroll
    for (int j = 0; j < BJ; j++)
      #pragma unroll
      for (int r = 0; r < 4; r++) acc[i][j][r] = 0.f;

  int arow[AI], brow[BJ];
  #pragma unroll
  for (int i = 0; i < AI; i++) arow[i] = wy * (TM / 2) + i * 16 + l15;
  #pragma unroll
  for (int j = 0; j < BJ; j++) brow[j] = wx * (TN / 2) + j * 16 + l15;

  const int iters = K >> 6;
  if (producer) {
    stage_rows<TN>(Bb, K, Bs[0], 0, pw, lane);        // B(0)
    stage_rows<TM>(Ab, K, As[0], 0, pw, lane);        // A(0)
    if (iters > 1) {
      stage_rows<TM>(Ab, K, As[1], 64, pw, lane);     // A(1) stays in flight
      waitcnt_vm<TM / 32>();
    } else {
      waitcnt_vm<0>();
    }
  }
  raw_barrier();
  int ac = 0;  // = it % 3
  for (int it = 0; it < iters; ++it) {
    if (producer) {
      const bool issueB = (it + 1 < iters);
      const bool issueA = (it + 2 < iters);
      if (issueB)
        stage_rows<TN>(Bb, K, Bs[(it + 1) & 1], (it + 1) << 6, pw, lane);
      if (issueA) {
        int an = ac + 2; if (an >= 3) an -= 3;       // (it+2) % 3
        stage_rows<TM>(Ab, K, As[an], (it + 2) << 6, pw, lane);
        waitcnt_vm<TM / 32>();                        // A(it+1),B(it+1) landed
      } else {
        waitcnt_vm<0>();
      }
    } else {
      const unsigned short* Ac = As[ac];
      const unsigned short* Bc = Bs[it & 1];
      #pragma unroll
      for (int h = 0; h < 2; h++) {
        bf16x8 afr[AI], bfr[BJ];
        #pragma unroll
        for (int i = 0; i < AI; i++)
          afr[i] = *(const bf16x8*)&Ac[frag_off64(arow[i], h * 4 + quad)];
        #pragma unroll
        for (int j = 0; j < BJ; j++)
          bfr[j] = *(const bf16x8*)&Bc[frag_off64(brow[j], h * 4 + quad)];
        #pragma unroll
        for (int i = 0; i < AI; i++)
          #pragma unroll
          for (int j = 0; j < BJ; j++)
            acc[i][j] = __builtin_amdgcn_mfma_f32_16x16x32_bf16(afr[i], bfr[j], acc[i][j], 0, 0, 0);
      }
    }
    raw_barrier();
    ac = (ac == 2) ? 0 : ac + 1;
  }

  if (producer) return;
  #pragma unroll
  for (int i = 0; i < AI; i++)
    #pragma unroll
    for (int j = 0; j < BJ; j++) {
      int gm = bm + wy * (TM / 2) + i * 16 + quad * 4;
      int gn = bn + wx * (TN / 2) + j * 16 + l15;
      #pragma unroll
      for (int r = 0; r < 4; r++) {
        float v = acc[i][j][r];
        size_t idx = (size_t)(gm + r) * N + gn;
        if (EPI == 0) outF[idx] = v;
        else if (EPI == 1) outB[idx] = f2bf(v);
        else if (EPI == 2) outB[idx] = f2bf(silu_f(v));
        else if (EPI == 3) outB[idx] = f2bf(v + bf2f(resB[idx]));
        else if (EPI == 4) outB[idx] = f2bf(v + resF[idx]);
      }
    }
}

// -- wave-specialized dual GEMM, mixed depth (A x3, G/I x2 = 80 KB) ----------
// Block tile 128(M) x 64(N); consumer wave 64x32 per output (64 acc regs).
__global__ __launch_bounds__(512, 4) void gemm_dual_ws(
    const unsigned short* __restrict__ A, const unsigned short* __restrict__ Bg,
    const unsigned short* __restrict__ Bi, int M, int N, int K,
    unsigned short* __restrict__ outH) {
  __shared__ __align__(16) unsigned short As[3][128 * 64];
  __shared__ __align__(16) unsigned short Gs[2][64 * 64];
  __shared__ __align__(16) unsigned short Is[2][64 * 64];
  const int tid = threadIdx.x;
  const int bm = blockIdx.y * 128, bn = blockIdx.x * 64;
  const int wave = tid >> 6, lane = tid & 63;
  const bool producer = wave >= 4;
  const int pw = wave & 3;
  const int wy = (wave & 3) >> 1, wx = wave & 1;
  const int l15 = lane & 15, quad = lane >> 4;

  const unsigned short* Ab = A + (size_t)bm * K;
  const unsigned short* Gb = Bg + (size_t)bn * K;
  const unsigned short* Ib = Bi + (size_t)bn * K;

  floatx4 accg[4][2], acci[4][2];
  #pragma unroll
  for (int i = 0; i < 4; i++)
    #pragma unroll
    for (int j = 0; j < 2; j++)
      #pragma unroll
      for (int r = 0; r < 4; r++) { accg[i][j][r] = 0.f; acci[i][j][r] = 0.f; }

  int arow[4], brow[2];
  #pragma unroll
  for (int i = 0; i < 4; i++) arow[i] = wy * 64 + i * 16 + l15;
  #pragma unroll
  for (int j = 0; j < 2; j++) brow[j] = wx * 32 + j * 16 + l15;

  const int iters = K >> 6;
  if (producer) {
    stage_rows<64>(Gb, K, Gs[0], 0, pw, lane);        // G(0)
    stage_rows<64>(Ib, K, Is[0], 0, pw, lane);        // I(0)
    stage_rows<128>(Ab, K, As[0], 0, pw, lane);       // A(0)
    if (iters > 1) {
      stage_rows<128>(Ab, K, As[1], 64, pw, lane);    // A(1) in flight
      waitcnt_vm<4>();
    } else {
      waitcnt_vm<0>();
    }
  }
  raw_barrier();
  int ac = 0;
  for (int it = 0; it < iters; ++it) {
    if (producer) {
      const bool issueB = (it + 1 < iters);
      const bool issueA = (it + 2 < iters);
      if (issueB) {
        stage_rows<64>(Gb, K, Gs[(it + 1) & 1], (it + 1) << 6, pw, lane);
        stage_rows<64>(Ib, K, Is[(it + 1) & 1], (it + 1) << 6, pw, lane);
      }
      if (issueA) {
        int an = ac + 2; if (an >= 3) an -= 3;
        stage_rows<128>(Ab, K, As[an], (it + 2) << 6, pw, lane);
        waitcnt_vm<4>();
      } else {
        waitcnt_vm<0>();
      }
    } else {
      const unsigned short* Ac = As[ac];
      const unsigned short* Gc = Gs[it & 1];
      const unsigned short* Ic = Is[it & 1];
      #pragma unroll
      for (int h = 0; h < 2; h++) {
        bf16x8 afr[4], gfr[2], ifr[2];
        #pragma unroll
        for (int i = 0; i < 4; i++)
          afr[i] = *(const bf16x8*)&Ac[frag_off64(arow[i], h * 4 + quad)];
        #pragma unroll
        for (int j = 0; j < 2; j++) {
          gfr[j] = *(const bf16x8*)&Gc[frag_off64(brow[j], h * 4 + quad)];
          ifr[j] = *(const bf16x8*)&Ic[frag_off64(brow[j], h * 4 + quad)];
        }
        #pragma unroll
        for (int i = 0; i < 4; i++)
          #pragma unroll
          for (int j = 0; j < 2; j++) {
            accg[i][j] = __builtin_amdgcn_mfma_f32_16x16x32_bf16(afr[i], gfr[j], accg[i][j], 0, 0, 0);
            acci[i][j] = __builtin_amdgcn_mfma_f32_16x16x32_bf16(afr[i], ifr[j], acci[i][j], 0, 0, 0);
          }
      }
    }
    raw_barrier();
    ac = (ac == 2) ? 0 : ac + 1;
  }

  if (producer) return;
  #pragma unroll
  for (int i = 0; i < 4; i++)
    #pragma unroll
    for (int j = 0; j < 2; j++) {
      int gm = bm + wy * 64 + i * 16 + quad * 4;
      int gn = bn + wx * 32 + j * 16 + l15;
      #pragma unroll
      for (int r = 0; r < 4; r++) {
        size_t idx = (size_t)(gm + r) * N + gn;
        outH[idx] = f2bf(silu_f(accg[i][j][r]) * acci[i][j][r]);
      }
    }
}

// ------- fused depthwise causal conv (K=5) + residual + rmsnorm -------
// outputs x2 = h + conv(h) and x2n = rmsnorm(x2). Vectorized LDS taps.
#define HS_LD 1040  // skewed row stride (elems): 2080 B -> rows shift 8 banks
__global__ __launch_bounds__(256) void conv_rms_kernel(const unsigned short* __restrict__ h,
                                                       const float* __restrict__ cw,
                                                       unsigned short* __restrict__ x2,
                                                       unsigned short* __restrict__ x2n) {
  int patch = blockIdx.x;  // 0..2047
  __shared__ __align__(16) unsigned short hs[16 * HS_LD];
  __shared__ __align__(16) float cwp[5 * 1024];  // [k][c] planes
  const int tid = threadIdx.x;
  size_t base = (size_t)patch * 16384;
  for (int idx = tid * 8; idx < 16384; idx += 256 * 8) {
    int row = idx >> 10, col = idx & 1023;
    *(uint4*)&hs[row * HS_LD + col] = *(const uint4*)&h[base + idx];
  }
  for (int i = tid; i < 5120; i += 256) {
    int c = i / 5, k = i - c * 5;
    cwp[k * 1024 + c] = cw[i];
  }
  __syncthreads();
  int t = tid >> 4;
  int lc = (tid & 15) * 8;
  float vals[8][8];
  float ss = 0.f;
  #pragma unroll
  for (int jb = 0; jb < 8; jb++) {
    int c = jb * 128 + lc;
    float tap[5][8];
    #pragma unroll
    for (int k = 0; k < 5; k++) {
      int tt = t + k - 4;
      if (tt >= 0) {
        uint4 v = *(const uint4*)&hs[tt * HS_LD + c];
        const unsigned short* vp = (const unsigned short*)&v;
        #pragma unroll
        for (int i = 0; i < 8; i++) tap[k][i] = bf2f(vp[i]);
      } else {
        #pragma unroll
        for (int i = 0; i < 8; i++) tap[k][i] = 0.f;
      }
    }
    float w[5][8];
    #pragma unroll
    for (int k = 0; k < 5; k++) {
      float4 a = *(const float4*)&cwp[k * 1024 + c];
      float4 b = *(const float4*)&cwp[k * 1024 + c + 4];
      w[k][0] = a.x; w[k][1] = a.y; w[k][2] = a.z; w[k][3] = a.w;
      w[k][4] = b.x; w[k][5] = b.y; w[k][6] = b.z; w[k][7] = b.w;
    }
    #pragma unroll
    for (int i = 0; i < 8; i++) {
      float acc = tap[4][i];  // residual (tap k=4 is row t itself)
      #pragma unroll
      for (int k = 0; k < 5; k++) acc += w[k][i] * tap[k][i];
      vals[jb][i] = acc;
      ss += acc * acc;
    }
  }
  ss += __shfl_down(ss, 8, 16);
  ss += __shfl_down(ss, 4, 16);
  ss += __shfl_down(ss, 2, 16);
  ss += __shfl_down(ss, 1, 16);
  ss = __shfl(ss, 0, 16);
  float sc = rsqrtf(ss * (1.f / 1024.f) + 1.1920929e-7f);
  #pragma unroll
  for (int jb = 0; jb < 8; jb++) {
    ushort4 o2[2], on[2];
    #pragma unroll
    for (int i = 0; i < 8; i++) {
      ((unsigned short*)o2)[i] = f2bf(vals[jb][i]);
      ((unsigned short*)on)[i] = f2bf(vals[jb][i] * sc);
    }
    size_t off = base + (size_t)t * 1024 + jb * 128 + lc;
    *(uint4*)&x2[off] = *(uint4*)o2;
    *(uint4*)&x2n[off] = *(uint4*)on;
  }
}

// ---------------- per-patch per-head attention (PS=16, HD=256) ----------------
__global__ __launch_bounds__(256) void attn_kernel(const unsigned short* __restrict__ qkv,
                                                   unsigned short* __restrict__ sa) {
  int patch = blockIdx.x;  // 0..2047
  int head = blockIdx.y;   // 0..3
  const int tid = threadIdx.x;
  __shared__ float qs[16][260], ks[16][260], vs[16][260];
  __shared__ float sc[16][16];
  size_t base = (size_t)patch * 16 * 3072 + (size_t)head * 256;
  for (int idx = tid * 8; idx < 16 * 256; idx += 256 * 8) {
    int t = idx >> 8, d = idx & 255;
    size_t roff = base + (size_t)t * 3072 + d;
    uint4 qv = *(const uint4*)&qkv[roff];
    uint4 kv = *(const uint4*)&qkv[roff + 1024];
    uint4 vv = *(const uint4*)&qkv[roff + 2048];
    const unsigned short* qp = (const unsigned short*)&qv;
    const unsigned short* kp = (const unsigned short*)&kv;
    const unsigned short* vp = (const unsigned short*)&vv;
    #pragma unroll
    for (int i = 0; i < 8; i++) {
      qs[t][d + i] = bf2f(qp[i]);
      ks[t][d + i] = bf2f(kp[i]);
      vs[t][d + i] = bf2f(vp[i]);
    }
  }
  __syncthreads();
  {
    int t = tid >> 4, kk = tid & 15;
    float s = 0.f;
    for (int d = 0; d < 256; d += 4) {
      float4 q = *(const float4*)&qs[t][d];
      float4 k = *(const float4*)&ks[kk][d];
      s += q.x * k.x + q.y * k.y + q.z * k.z + q.w * k.w;
    }
    sc[t][kk] = s * 0.0625f;  // HD^-0.5
  }
  __syncthreads();
  if (tid < 16) {
    float m = -1e30f;
    for (int kk = 0; kk < 16; kk++) m = fmaxf(m, sc[tid][kk]);
    float p[16], sum = 0.f;
    for (int kk = 0; kk < 16; kk++) { p[kk] = __expf(sc[tid][kk] - m); sum += p[kk]; }
    float inv = 1.f / sum;
    for (int kk = 0; kk < 16; kk++) sc[tid][kk] = p[kk] * inv;
  }
  __syncthreads();
  for (int idx = tid * 8; idx < 4096; idx += 256 * 8) {
    int t = idx >> 8, d = idx & 255;
    float o[8] = {0, 0, 0, 0, 0, 0, 0, 0};
    #pragma unroll
    for (int kk = 0; kk < 16; kk++) {
      float w = sc[t][kk];
      float4 v0 = *(const float4*)&vs[kk][d];
      float4 v1 = *(const float4*)&vs[kk][d + 4];
      o[0] += w * v0.x; o[1] += w * v0.y; o[2] += w * v0.z; o[3] += w * v0.w;
      o[4] += w * v1.x; o[5] += w * v1.y; o[6] += w * v1.z; o[7] += w * v1.w;
    }
    ushort4 ov[2];
    #pragma unroll
    for (int i = 0; i < 8; i++) ((unsigned short*)ov)[i] = f2bf(o[i]);
    *(uint4*)&sa[(size_t)(patch * 16 + t) * 1024 + head * 256 + d] = *(uint4*)ov;
  }
}

// -- head pooling with FUSED rmsnorm(x3) input + fused rmsnorm(pooled) out --
__global__ __launch_bounds__(256) void pool_kernel(const unsigned short* __restrict__ x3,
                                                   const float* __restrict__ wpool,
                                                   const float* __restrict__ tptr,
                                                   float* __restrict__ pooled,
                                                   unsigned short* __restrict__ pooledn) {
  int patch = blockIdx.x;  // 0..2047
  __shared__ __align__(16) unsigned short xs[16 * 1024];
  __shared__ float lg[4][16], aw[4][16], srow[16];
  const int tid = threadIdx.x;
  size_t base = (size_t)patch * 16384;
  for (int idx = tid * 8; idx < 16384; idx += 256 * 8)
    *(uint4*)&xs[idx] = *(const uint4*)&x3[base + idx];
  __syncthreads();
  {  // per-row sum of squares: row t = tid>>4, 64 elems per lane
    int t = tid >> 4, sub = tid & 15;
    float ss = 0.f;
    for (int d = sub * 64; d < sub * 64 + 64; d += 4) {
      uint2 v = *(const uint2*)&xs[t * 1024 + d];
      const unsigned short* vp = (const unsigned short*)&v;
      #pragma unroll
      for (int i = 0; i < 4; i++) { float x = bf2f(vp[i]); ss += x * x; }
    }
    ss += __shfl_down(ss, 8, 16);
    ss += __shfl_down(ss, 4, 16);
    ss += __shfl_down(ss, 2, 16);
    ss += __shfl_down(ss, 1, 16);
    if (sub == 0) srow[t] = rsqrtf(ss * (1.f / 1024.f) + 1.1920929e-7f);
  }
  __syncthreads();
  {
    int pair = tid >> 2, sub = tid & 3;
    int t = pair >> 2, hh = pair & 3;
    float s = 0.f;
    for (int d = sub * 256; d < sub * 256 + 256; d++)
      s += bf2f(xs[t * 1024 + d]) * wpool[hh * 1024 + d];
    s += __shfl_down(s, 2, 64);
    s += __shfl_down(s, 1, 64);
    if (sub == 0) {
      float temp = fmaxf(tptr[0], 0.01f);
      lg[hh][t] = s * srow[t] / temp;
    }
  }
  __syncthreads();
  if (tid < 4) {
    int hh = tid;
    float m = -1e30f;
    for (int t = 0; t < 16; t++) m = fmaxf(m, lg[hh][t]);
    float p[16], sum = 0.f;
    for (int t = 0; t < 16; t++) { p[t] = __expf(lg[hh][t] - m); sum += p[t]; }
    float inv = 1.f / sum;
    for (int t = 0; t < 16; t++) aw[hh][t] = p[t] * inv;
  }
  __syncthreads();
  float ov[4]; int cs[4];
  float ss = 0.f;
  #pragma unroll
  for (int q = 0; q < 4; q++) {
    int c = tid + q * 256;
    int hh = c >> 8;
    float o = 0.f;
    #pragma unroll
    for (int t = 0; t < 16; t++) o += aw[hh][t] * srow[t] * bf2f(xs[t * 1024 + c]);
    ov[q] = o; cs[q] = c;
    ss += o * o;
  }
  ss = block_reduce_sum(ss);
  float scn = rsqrtf(ss * (1.f / 1024.f) + 1.1920929e-7f);
  #pragma unroll
  for (int q = 0; q < 4; q++) {
    pooled[(size_t)patch * 1024 + cs[q]] = ov[q];
    pooledn[(size_t)patch * 1024 + cs[q]] = f2bf(ov[q] * scn);
  }
}

extern "C" void kernel_launch(void* const* d_in, const int* in_sizes, int n_in,
                              void* d_out, int out_size, void* d_ws, size_t ws_size,
                              hipStream_t stream) {
  (void)in_sizes; (void)n_in; (void)out_size; (void)ws_size;
  const float* pbe  = (const float*)d_in[0];   // (4,512,16,1024)
  const float* lpos = (const float*)d_in[1];   // (16,1024)
  const float* wg   = (const float*)d_in[2];
  const float* wi   = (const float*)d_in[3];
  const float* cw   = (const float*)d_in[4];   // (1024,1,5)
  const float* wqkv = (const float*)d_in[5];   // (3072,1024)
  const float* wio  = (const float*)d_in[6];
  const float* wpl  = (const float*)d_in[7];   // (4,1024)
  const float* temp = (const float*)d_in[8];
  const float* wup  = (const float*)d_in[9];
  const float* wdn  = (const float*)d_in[10];
  const float* wout = (const float*)d_in[11];
  float* outp = (float*)d_out;                 // (4,512,1024) fp32

  const int ROWS = 32768, Dm = 1024, NPAT = 2048;

  char* p = (char*)d_ws;
  auto take = [&](size_t nbytes) { void* r = (void*)p; p += (nbytes + 255) & ~(size_t)255; return r; };
  unsigned short* wg_b   = (unsigned short*)take((size_t)Dm * Dm * 2);
  unsigned short* wi_b   = (unsigned short*)take((size_t)Dm * Dm * 2);
  unsigned short* wqkv_b = (unsigned short*)take((size_t)3 * Dm * Dm * 2);
  unsigned short* wio_b  = (unsigned short*)take((size_t)Dm * Dm * 2);
  unsigned short* wup_b  = (unsigned short*)take((size_t)Dm * Dm * 2);
  unsigned short* wdn_b  = (unsigned short*)take((size_t)Dm * Dm * 2);
  unsigned short* wout_b = (unsigned short*)take((size_t)Dm * Dm * 2);
  unsigned short* slotA  = (unsigned short*)take((size_t)ROWS * Dm * 2);  // xn / x2n
  unsigned short* slotB  = (unsigned short*)take((size_t)ROWS * Dm * 2);  // h / sa
  unsigned short* slotC  = (unsigned short*)take((size_t)ROWS * Dm * 2);  // x2 / x3
  unsigned short* qkvB   = (unsigned short*)take((size_t)ROWS * 3 * Dm * 2);
  float*          pooled = (float*)take((size_t)NPAT * Dm * 4);
  unsigned short* pooledn= (unsigned short*)take((size_t)NPAT * Dm * 2);
  unsigned short* ubuf   = (unsigned short*)take((size_t)NPAT * Dm * 2);
  unsigned short* y1b    = (unsigned short*)take((size_t)NPAT * Dm * 2);
  float*          y2     = (float*)take((size_t)NPAT * Dm * 4);

  // 0. all weight conversions in one launch
  CvtArgs ca;
  ca.src[0] = wg;   ca.dst[0] = wg_b;
  ca.src[1] = wi;   ca.dst[1] = wi_b;
  ca.src[2] = wqkv; ca.dst[2] = wqkv_b;
  ca.src[3] = wio;  ca.dst[3] = wio_b;
  ca.src[4] = wup;  ca.dst[4] = wup_b;
  ca.src[5] = wdn;  ca.dst[5] = wdn_b;
  ca.src[6] = wout; ca.dst[6] = wout_b;
  int off = 0;
  for (int i = 0; i < 7; i++) { ca.blkoff[i] = off; off += (i == 2) ? 3072 : 1024; }
  ca.blkoff[7] = off;
  cvt_all<<<dim3(off), dim3(256), 0, stream>>>(ca);

  // 1. xn = rmsnorm(pbe + pos)
  prep_kernel<<<dim3(ROWS), dim3(256), 0, stream>>>(pbe, lpos, slotA);
  // 2. h = silu(xn@wg^T) * (xn@wi^T)
  gemm_dual_ws<<<dim3(Dm / 64, ROWS / 128), dim3(512), 0, stream>>>(
      slotA, wg_b, wi_b, ROWS, Dm, Dm, slotB);
  // 3+4. x2 = h + conv(h); x2n = rmsnorm(x2)
  conv_rms_kernel<<<dim3(NPAT), dim3(256), 0, stream>>>(slotB, cw, slotC, slotA);
  // 5. qkv = x2n @ wqkv^T
  gemm_ws<1, 128, 128><<<dim3(3 * Dm / 128, ROWS / 128), dim3(512), 0, stream>>>(
      slotA, wqkv_b, ROWS, 3 * Dm, Dm, nullptr, qkvB, nullptr, nullptr);
  // 6. sa = attention(qkv)
  attn_kernel<<<dim3(NPAT, 4), dim3(256), 0, stream>>>(qkvB, slotB);
  // 7. x3 = x2 + sa @ wio^T   (in-place into slotC)
  gemm_ws<3, 128, 128><<<dim3(Dm / 128, ROWS / 128), dim3(512), 0, stream>>>(
      slotB, wio_b, ROWS, Dm, Dm, nullptr, slotC, slotC, nullptr);
  // 8+9+10. pooled = softmax-pool(rmsnorm(x3)); pooledn = rmsnorm(pooled)
  pool_kernel<<<dim3(NPAT), dim3(256), 0, stream>>>(slotC, wpl, temp, pooled, pooledn);
  // 11. u = silu(pooledn @ wup^T)
  gemm_ws<2, 64, 128><<<dim3(Dm / 128, NPAT / 64), dim3(512), 0, stream>>>(
      pooledn, wup_b, NPAT, Dm, Dm, nullptr, ubuf, nullptr, nullptr);
  // 12. y1 = pooled + u @ wdn^T
  gemm_ws<4, 64, 128><<<dim3(Dm / 128, NPAT / 64), dim3(512), 0, stream>>>(
      ubuf, wdn_b, NPAT, Dm, Dm, nullptr, y1b, nullptr, pooled);
  // 13. y2 = y1 @ wout^T
  gemm_ws<0, 64, 128><<<dim3(Dm / 128, NPAT / 64), dim3(512), 0, stream>>>(
      y1b, wout_b, NPAT, Dm, Dm, y2, nullptr, nullptr, nullptr);
  // 14. out = rmsnorm(y2)
  rmsnorm_kernel<float, float><<<dim3(NPAT), dim3(256), 0, stream>>>(y2, outp);
}